// Round 1
// 153.522 us; speedup vs baseline: 1.0215x; 1.0215x over previous
//
#include <hip/hip_runtime.h>
#include <hip/hip_bf16.h>

typedef __bf16 bf16_t;
typedef __bf16 bf16x4 __attribute__((ext_vector_type(4)));
typedef __bf16 bf16x8 __attribute__((ext_vector_type(8)));
typedef float floatx4 __attribute__((ext_vector_type(4)));

#define N_NODES 4096
#define F_IN 128
#define NUM_HEADS 4
#define D_HID 64
#define F_OUT 256  // NUM_HEADS * D_HID
#define NEG_SLOPE 0.2f

// async global->LDS, 16 B per lane (wave-uniform LDS base + lane*16 layout)
__device__ __forceinline__ void async_copy16(const void* gsrc, void* ldst)
{
    __builtin_amdgcn_global_load_lds(
        (const __attribute__((address_space(1))) unsigned int*)gsrc,
        (__attribute__((address_space(3))) unsigned int*)ldst,
        16, 0, 0);
}

// ---------------------------------------------------------------------------
// Kernel 1: projections (f32 in; GB bf16 fragment-linear + el/er f32 out).
//   g[j][h*64+f] stored into GB so that a B-fragment (16x16x32 bf16 MFMA) is a
//   contiguous 1 KB block: GB[h][j>>5][f>>4][lane=(f&15)+16*((j>>3)&3)][j&7].
//   el[h][j] = <ga[j,h,:], w_attn[:32]>   er[h][j] = <ga[j,h,:], w_attn[32:]>
// 1024 blocks x 384 threads; block handles 4 nodes.
// h reads are wave-uniform -> s_load broadcast; no LDS, no __syncthreads.
// ---------------------------------------------------------------------------
__global__ __launch_bounds__(384) void proj_kernel(
    const float* __restrict__ hmat, const float* __restrict__ Wp,
    const float* __restrict__ Wa, const float* __restrict__ wattn,
    bf16_t* __restrict__ GB, float* __restrict__ el, float* __restrict__ er)
{
    const int t = threadIdx.x;
    const int j0 = blockIdx.x * 4;

    float acc[4] = {0.f, 0.f, 0.f, 0.f};

    const float* wptr;
    int stride;
    if (t < 256) { wptr = Wp + t;         stride = 256; }
    else         { wptr = Wa + (t - 256); stride = 128; }

    const float* hbase = hmat + (size_t)j0 * F_IN;

    for (int m = 0; m < F_IN; m += 4) {
        const float w0 = wptr[(size_t)(m + 0) * stride];
        const float w1 = wptr[(size_t)(m + 1) * stride];
        const float w2 = wptr[(size_t)(m + 2) * stride];
        const float w3 = wptr[(size_t)(m + 3) * stride];
#pragma unroll
        for (int jl = 0; jl < 4; ++jl) {
            // uniform address across the wave -> scalar load broadcast
            const float4 hv = *reinterpret_cast<const float4*>(&hbase[jl * F_IN + m]);
            acc[jl] = fmaf(hv.w, w3, fmaf(hv.z, w2, fmaf(hv.y, w1, fmaf(hv.x, w0, acc[jl]))));
        }
    }

    if (t < 256) {
        const int h = t >> 6, f = t & 63;
        bf16x4 o;
#pragma unroll
        for (int q = 0; q < 4; ++q) o[q] = (bf16_t)acc[q];
        // fragment-linear GB element offset (bf16 elems)
        const size_t base = ((((size_t)h * 128 + (j0 >> 5)) * 4 + (f >> 4)) * 64
                             + (f & 15) + 16 * ((j0 >> 3) & 3)) * 8 + (j0 & 7);
        *reinterpret_cast<bf16x4*>(&GB[base]) = o;
    } else {
        const int ta = t - 256;          // waves 4,5; 32-lane group per head
        const int ha = ta >> 5, k = ta & 31;
        const float wl = wattn[k], wr = wattn[32 + k];
#pragma unroll
        for (int jl = 0; jl < 4; ++jl) {
            float vl = acc[jl] * wl;
            float vr = acc[jl] * wr;
#pragma unroll
            for (int s = 16; s >= 1; s >>= 1) {
                vl += __shfl_xor(vl, s, 64);
                vr += __shfl_xor(vr, s, 64);
            }
            if (k == 0) {
                el[ha * N_NODES + j0 + jl] = vl;
                er[ha * N_NODES + j0 + jl] = vr;
            }
        }
    }
}

// ---------------------------------------------------------------------------
// Kernel 2: LDS-tiled fused attention.
// Grid (128 i-tiles of 32 rows, njc) x 512 threads (8 waves).
// LDS = P_s 16 KB + GB_s 32 KB = 48 KB -> 3 blocks/CU resident; barriers now
// sync 8 waves with 2-3 independent blocks/CU hiding each other's drains.
// GB tile staged via global_load_lds width-16 (no VGPR round-trip); adj
// register-prefetched one tile ahead; den via ones-MFMA as before.
// ---------------------------------------------------------------------------
__global__ __launch_bounds__(512, 6) void attn_kernel(
    const float* __restrict__ adj, const bf16_t* __restrict__ GB,
    const float* __restrict__ el, const float* __restrict__ er,
    float* __restrict__ numout, float* __restrict__ den_g,
    int njc, int ntiles)
{
    __shared__ bf16_t P_s[NUM_HEADS * 32 * 64];   // 16 KiB
    __shared__ bf16_t GB_s[32 * 512];             // 32 KiB (32 subs x 1 KB)

    const int tid = threadIdx.x;
    const int i0  = blockIdx.x * 32;
    const int jc  = blockIdx.y;
    const int jT0 = jc * ntiles * 64;

    // phase-1 identity: thread -> (block-local i, tile-local j*4)
    const int pi   = tid >> 4;            // 0..31
    const int pj4  = (tid & 15) << 2;     // 0,4,..,60
    const int glog = pj4 >> 3;            // j-group 0..7
    const int goff = pj4 & 7;             // 0 or 4
    const int psw  = ((glog ^ (pi & 7)) << 3) + goff;   // swizzled in-row offset

    // phase-2 identity
    const int wave = tid >> 6;            // 0..7
    const int hh   = wave >> 1;           // head
    const int mt   = wave & 1;            // m-tile (16 rows)
    const int lane = tid & 63;
    const int m    = lane & 15;
    const int quad = lane >> 4;

    float elr[NUM_HEADS];
#pragma unroll
    for (int h = 0; h < NUM_HEADS; ++h) elr[h] = el[h * N_NODES + i0 + pi];

    const float* adjp = adj + (size_t)(i0 + pi) * N_NODES + pj4;

    // GB staging: wave stages subs wave*4 .. wave*4+3; sub s=(jbL*16)+(h*4)+fg
    const int sb = wave * 4;

    floatx4 acc0 = {0.f, 0.f, 0.f, 0.f};
    floatx4 acc1 = acc0, acc2 = acc0, acc3 = acc0, accd = acc0;
    bf16x8 ones;
#pragma unroll
    for (int q = 0; q < 8; ++q) ones[q] = (bf16_t)1.0f;

    // prologue: prefetch adj tile 0
    float4 adjv = *reinterpret_cast<const float4*>(adjp + jT0);

    for (int k = 0; k < ntiles; ++k) {
        const int jT   = jT0 + k * 64;
        const int jb32 = jT >> 5;
        // ---------- issue async GB staging for THIS tile (completes at barrier) ----------
#pragma unroll
        for (int q = 0; q < 4; ++q) {
            const int s  = sb + q;
            const int sj = s >> 4, sh = (s >> 2) & 3, sf = s & 3;
            const bf16_t* gsrc =
                GB + ((size_t)(sh * 128 + jb32 + sj) * 4 + sf) * 512 + lane * 8;
            async_copy16(gsrc, &GB_s[s * 512 + lane * 8]);
        }
        // prefetch next adj tile into registers (overlaps both phases)
        float4 adjn;
        if (k + 1 < ntiles)
            adjn = *reinterpret_cast<const float4*>(adjp + jT + 64);
        // ---------- phase 1: P for 4 heads at (pi, pj4..pj4+3) ----------
        const bool k0 = adjv.x >= 0.5f, k1 = adjv.y >= 0.5f,
                   k2 = adjv.z >= 0.5f, k3 = adjv.w >= 0.5f;
#pragma unroll
        for (int h = 0; h < NUM_HEADS; ++h) {
            const float4 ev = *reinterpret_cast<const float4*>(er + h * N_NODES + jT + pj4);
            float e0 = elr[h] + ev.x, e1 = elr[h] + ev.y,
                  e2 = elr[h] + ev.z, e3 = elr[h] + ev.w;
            e0 = fmaxf(e0, NEG_SLOPE * e0);
            e1 = fmaxf(e1, NEG_SLOPE * e1);
            e2 = fmaxf(e2, NEG_SLOPE * e2);
            e3 = fmaxf(e3, NEG_SLOPE * e3);
            bf16x4 pv;
            pv[0] = (bf16_t)(k0 ? __expf(e0) : 0.f);
            pv[1] = (bf16_t)(k1 ? __expf(e1) : 0.f);
            pv[2] = (bf16_t)(k2 ? __expf(e2) : 0.f);
            pv[3] = (bf16_t)(k3 ? __expf(e3) : 0.f);
            *reinterpret_cast<bf16x4*>(&P_s[(h * 32 + pi) * 64 + psw]) = pv;
        }
        __syncthreads();   // drains vmcnt (GB_s) + lgkmcnt (P_s): both ready
        // ---------- phase 2 ----------
        __builtin_amdgcn_s_setprio(1);
#pragma unroll
        for (int kt = 0; kt < 2; ++kt) {
            const int gphys = (((kt * 4 + quad) ^ (m & 7)) << 3);
            const bf16x8 af = *reinterpret_cast<const bf16x8*>(
                &P_s[(hh * 32 + mt * 16 + m) * 64 + gphys]);
            accd = __builtin_amdgcn_mfma_f32_16x16x32_bf16(af, ones, accd, 0, 0, 0);
            const int bb = (kt * 16 + hh * 4) * 512 + lane * 8;
            const bf16x8 b0 = *reinterpret_cast<const bf16x8*>(&GB_s[bb]);
            const bf16x8 b1 = *reinterpret_cast<const bf16x8*>(&GB_s[bb + 512]);
            const bf16x8 b2 = *reinterpret_cast<const bf16x8*>(&GB_s[bb + 1024]);
            const bf16x8 b3 = *reinterpret_cast<const bf16x8*>(&GB_s[bb + 1536]);
            acc0 = __builtin_amdgcn_mfma_f32_16x16x32_bf16(af, b0, acc0, 0, 0, 0);
            acc1 = __builtin_amdgcn_mfma_f32_16x16x32_bf16(af, b1, acc1, 0, 0, 0);
            acc2 = __builtin_amdgcn_mfma_f32_16x16x32_bf16(af, b2, acc2, 0, 0, 0);
            acc3 = __builtin_amdgcn_mfma_f32_16x16x32_bf16(af, b3, acc3, 0, 0, 0);
        }
        __builtin_amdgcn_s_setprio(0);
        if (k + 1 < ntiles) adjv = adjn;
        __syncthreads();   // P_s/GB_s consumed; safe to overwrite next iter
    }

    // epilogue: C/D row = mt*16 + quad*4 + r, col = m; den replicated in accd[r]
    const int ibase = i0 + mt * 16 + quad * 4;
    if (njc == 1) {
#pragma unroll
        for (int r = 0; r < 4; ++r) {
            const float rd = 1.0f / accd[r];
            float* dst = numout + (size_t)(ibase + r) * F_OUT + hh * D_HID + m;
            dst[0]  = acc0[r] * rd;
            dst[16] = acc1[r] * rd;
            dst[32] = acc2[r] * rd;
            dst[48] = acc3[r] * rd;
        }
    } else {
        float* nrow = numout + (size_t)jc * ((size_t)N_NODES * F_OUT);
#pragma unroll
        for (int r = 0; r < 4; ++r) {
            float* dst = nrow + (size_t)(ibase + r) * F_OUT + hh * D_HID + m;
            dst[0]  = acc0[r];
            dst[16] = acc1[r];
            dst[32] = acc2[r];
            dst[48] = acc3[r];
        }
        if (m == 0) {
#pragma unroll
            for (int r = 0; r < 4; ++r)
                den_g[((size_t)jc * N_NODES + ibase + r) * NUM_HEADS + hh] = accd[r];
        }
    }
}

// ---------------------------------------------------------------------------
// Kernel 3 (njc>1): sum chunk partials, divide, store f32. Templated njc so
// the partial loop fully unrolls (all loads issued before any wait).
// ---------------------------------------------------------------------------
template<int NJC>
__global__ __launch_bounds__(256) void reduce_kernel(
    const float* __restrict__ num, const float* __restrict__ den,
    float* __restrict__ out)
{
    const int idx = blockIdx.x * 256 + threadIdx.x;  // 0 .. N*F_OUT-1
    const int i  = idx >> 8;
    const int c  = idx & 255;
    const int hh = c >> 6;
    float n = 0.f, d = 0.f;
#pragma unroll
    for (int jc = 0; jc < NJC; ++jc) {
        n += num[(size_t)jc * ((size_t)N_NODES * F_OUT) + idx];
        d += den[((size_t)jc * N_NODES + i) * NUM_HEADS + hh];
    }
    out[idx] = n / d;
}

// ---------------------------------------------------------------------------
extern "C" void kernel_launch(void* const* d_in, const int* in_sizes, int n_in,
                              void* d_out, int out_size, void* d_ws, size_t ws_size,
                              hipStream_t stream)
{
    const float* hmat = (const float*)d_in[0];   // (4096, 128) f32
    const float* adj  = (const float*)d_in[1];   // (4096, 4096) f32
    const float* Wp   = (const float*)d_in[2];   // (128, 256) f32
    const float* Wa   = (const float*)d_in[3];   // (128, 128) f32
    const float* watt = (const float*)d_in[4];   // (64,) f32
    float* out = (float*)d_out;                  // (4096, 256) f32

    char* ws = (char*)d_ws;
    bf16_t* GB = (bf16_t*)ws;                                  // 2 MiB
    float*  el = (float*)(ws + (2ull << 20));                  // 64 KiB
    float*  er = (float*)(ws + (2ull << 20) + (64ull << 10));  // 64 KiB
    const size_t baseoff = (2ull << 20) + (128ull << 10);

    const size_t num_bytes = (size_t)N_NODES * F_OUT * 4;          // 4 MiB per chunk
    const size_t den_bytes = (size_t)N_NODES * NUM_HEADS * 4;      // 64 KiB per chunk
    // ws >= ~18.8 MB proven (njc=4 ran); prefer 8 chunks for 3 blocks/CU.
    const int njc = (ws_size >= baseoff + 8 * (num_bytes + den_bytes)) ? 8
                  : (ws_size >= baseoff + 4 * (num_bytes + den_bytes)) ? 4 : 2;

    float* num = (float*)(ws + baseoff);
    float* den = (float*)(ws + baseoff + (size_t)njc * num_bytes);

    proj_kernel<<<1024, 384, 0, stream>>>(hmat, Wp, Wa, watt, GB, el, er);
    attn_kernel<<<dim3(128, njc), 512, 0, stream>>>(adj, GB, el, er, num, den,
                                                    njc, (N_NODES / njc) / 64);
    if (njc == 8)      reduce_kernel<8><<<(N_NODES * F_OUT) / 256, 256, 0, stream>>>(num, den, out);
    else if (njc == 4) reduce_kernel<4><<<(N_NODES * F_OUT) / 256, 256, 0, stream>>>(num, den, out);
    else               reduce_kernel<2><<<(N_NODES * F_OUT) / 256, 256, 0, stream>>>(num, den, out);
}